// Round 1
// baseline (832.407 us; speedup 1.0000x reference)
//
#include <hip/hip_runtime.h>
#include <hip/hip_bf16.h>
#include <math.h>

#define NB 128   // batch (both images and captions)
#define NR 36    // regions
#define NW 32    // words
#define ND 256   // feature dim

__device__ __constant__ float c_MARGIN = 0.05f;
__device__ __constant__ float c_TEMP   = 14.0f;

#define LAMf 9.0f
#define EPSf 1e-8f

// LDS strides (floats). 260 keeps float4 alignment (260*4 = 1040 B, 16B multiple)
#define IM_STRIDE 260
#define CAP_STRIDE 260

__global__ __launch_bounds__(256) void scores_kernel(
    const float* __restrict__ im,      // (NB, NR, ND)
    const float* __restrict__ s,       // (NB, NW, ND)
    const int*   __restrict__ s_l,     // (NB,)
    const float* __restrict__ im_mask, // (NB, NR)
    float* __restrict__ scores)        // (NB images, NB captions)
{
    const int c = blockIdx.x;   // caption index
    const int b = blockIdx.y;   // image index
    const int tid = threadIdx.x;

    __shared__ float s_im[NR * IM_STRIDE];
    __shared__ float s_cap[NW * CAP_STRIDE];
    __shared__ float s_attn[NR * 33];   // X[r][w]
    __shared__ float s_y[NW * 37];      // y[w][r]
    __shared__ float s_m[NR];
    __shared__ float s_nrm[NR];
    __shared__ float s_cos[NW];

    const int sl = s_l[c];

    // ---- stage im[b] into LDS (float4) ----
    const float4* im4 = (const float4*)(im + (size_t)b * NR * ND);
    for (int i = tid; i < NR * (ND / 4); i += 256) {
        int r = i >> 6, d4 = i & 63;
        float4 v = im4[i];
        *(float4*)&s_im[r * IM_STRIDE + 4 * d4] = v;
    }
    // ---- stage cap = s[c] * wordmask into LDS ----
    const float4* s4 = (const float4*)(s + (size_t)c * NW * ND);
    for (int i = tid; i < NW * (ND / 4); i += 256) {
        int w = i >> 6, d4 = i & 63;
        float4 v = s4[i];
        if (w >= sl) { v.x = 0.f; v.y = 0.f; v.z = 0.f; v.w = 0.f; }
        *(float4*)&s_cap[w * CAP_STRIDE + 4 * d4] = v;
    }
    if (tid < NR) s_m[tid] = im_mask[b * NR + tid];
    __syncthreads();

    // ---- attn[r][w] = leaky(dot(im[r], cap[w])) ; X = attn + (1-m[r]) ----
    {
        const int w = tid & 31;
        const int rg = tid >> 5;              // 0..7
        const int nr = (rg < NR - 32) ? 5 : 4; // rg<4 -> 5 rows, else 4
        float acc[5] = {0.f, 0.f, 0.f, 0.f, 0.f};
        for (int d4 = 0; d4 < ND / 4; ++d4) {
            const float4 cv = *(const float4*)&s_cap[w * CAP_STRIDE + 4 * d4];
#pragma unroll
            for (int k = 0; k < 5; ++k) {
                if (k < nr) {
                    const int r = rg + 8 * k;
                    const float4 iv = *(const float4*)&s_im[r * IM_STRIDE + 4 * d4];
                    acc[k] += iv.x * cv.x + iv.y * cv.y + iv.z * cv.z + iv.w * cv.w;
                }
            }
        }
#pragma unroll
        for (int k = 0; k < 5; ++k) {
            if (k < nr) {
                const int r = rg + 8 * k;
                float v = acc[k];
                v = (v >= 0.f) ? v : 0.1f * v;        // leaky_relu 0.1
                const float m = s_m[r];
                s_attn[r * 33 + w] = v + (1.f - m);   // X
            }
        }
    }
    __syncthreads();

    // ---- per-region norm over w: nrm[r] = sqrt(sum_w X^2) + EPS ----
    if (tid < NR) {
        float sum = 0.f;
        for (int w = 0; w < NW; ++w) {
            float x = s_attn[tid * 33 + w];
            sum += x * x;
        }
        s_nrm[tid] = sqrtf(sum) + EPSf;
    }
    __syncthreads();

    // ---- softmax over r (per w), masked by im_mask; y[w][r] ----
    if (tid < NW) {
        const int w = tid;
        float xs[NR];
        float mx = -1e30f;
#pragma unroll
        for (int r = 0; r < NR; ++r) {
            float a = s_attn[r * 33 + w] / s_nrm[r] * s_m[r]; // masked r -> exactly 0
            float x = a * LAMf;
            xs[r] = x;
            mx = fmaxf(mx, x);
        }
        float sum = 0.f;
#pragma unroll
        for (int r = 0; r < NR; ++r) {
            float e = __expf(xs[r] - mx) * s_m[r];
            xs[r] = e;
            sum += e;
        }
        const float inv = 1.f / sum;
#pragma unroll
        for (int r = 0; r < NR; ++r) s_y[w * 37 + r] = xs[r] * inv;
    }
    __syncthreads();

    // ---- wctx[w][d] = sum_r im[r][d]*y[w][r]; fuse w12, n1, n2 ----
    {
        const int w = tid >> 3;   // 0..31
        const int g = tid & 7;    // 8 threads per w, each 8 float4 chunks
        float w12 = 0.f, n2 = 0.f, n1 = 0.f;
        for (int j = 0; j < 8; ++j) {
            const int d4 = g + 8 * j;
            float4 wc = {0.f, 0.f, 0.f, 0.f};
#pragma unroll 4
            for (int r = 0; r < NR; ++r) {
                const float yv = s_y[w * 37 + r];
                const float4 iv = *(const float4*)&s_im[r * IM_STRIDE + 4 * d4];
                wc.x += yv * iv.x; wc.y += yv * iv.y;
                wc.z += yv * iv.z; wc.w += yv * iv.w;
            }
            const float4 cv = *(const float4*)&s_cap[w * CAP_STRIDE + 4 * d4];
            w12 += cv.x * wc.x + cv.y * wc.y + cv.z * wc.z + cv.w * wc.w;
            n2  += wc.x * wc.x + wc.y * wc.y + wc.z * wc.z + wc.w * wc.w;
            n1  += cv.x * cv.x + cv.y * cv.y + cv.z * cv.z + cv.w * cv.w;
        }
#pragma unroll
        for (int k = 4; k; k >>= 1) {
            w12 += __shfl_down(w12, k, 8);
            n2  += __shfl_down(n2, k, 8);
            n1  += __shfl_down(n1, k, 8);
        }
        if (g == 0) {
            const float cosv = w12 / fmaxf(sqrtf(n1) * sqrtf(n2), EPSf);
            s_cos[w] = (w < sl) ? cosv : 0.f;
        }
    }
    __syncthreads();

    if (tid == 0) {
        float sum = 0.f;
        for (int w = 0; w < NW; ++w) sum += s_cos[w];
        scores[b * NB + c] = sum / (float)sl;  // scores[image][caption]
    }
}

__global__ __launch_bounds__(128) void loss_kernel(
    const float* __restrict__ scores,  // (NB, NB)
    const int*   __restrict__ qid,
    float* __restrict__ out)
{
    __shared__ int   s_q[NB];
    __shared__ float s_c[NB];
    __shared__ float s_v[NB];
    const int i = threadIdx.x;
    s_q[i] = qid[i];
    __syncthreads();

    const int q = s_q[i];
    bool dup = false;
    for (int j = 0; j < i; ++j) dup = dup || (s_q[j] == q);

    const float* row = scores + i * NB;
    float mx = -1e30f;
    for (int j = 0; j < NB; ++j) {
        float l = (row[j] - ((j == i) ? c_MARGIN : 0.f)) * c_TEMP;
        mx = fmaxf(mx, l);
    }
    float sum = 0.f;
    for (int j = 0; j < NB; ++j) {
        float l = (row[j] - ((j == i) ? c_MARGIN : 0.f)) * c_TEMP;
        sum += expf(l - mx);
    }
    const float logZ = mx + logf(sum);
    const float picked = (row[i] - c_MARGIN) * c_TEMP;
    const float valid = dup ? 0.f : 1.f;
    s_c[i] = (logZ - picked) * valid;
    s_v[i] = valid;
    __syncthreads();
    if (i == 0) {
        float a = 0.f, v = 0.f;
        for (int j = 0; j < NB; ++j) { a += s_c[j]; v += s_v[j]; }
        out[0] = a / fmaxf(v, 1.f);
    }
}

extern "C" void kernel_launch(void* const* d_in, const int* in_sizes, int n_in,
                              void* d_out, int out_size, void* d_ws, size_t ws_size,
                              hipStream_t stream) {
    const float* im      = (const float*)d_in[0];
    const float* s       = (const float*)d_in[1];
    const int*   s_l     = (const int*)d_in[2];
    const float* im_mask = (const float*)d_in[3];
    const int*   qid     = (const int*)d_in[4];
    // d_in[5] class_scores, d_in[6] class_labels: unused by reference output

    float* scores = (float*)d_ws;      // NB*NB floats = 64 KB
    float* out    = (float*)d_out;

    dim3 grid(NB, NB);
    scores_kernel<<<grid, 256, 0, stream>>>(im, s, s_l, im_mask, scores);
    loss_kernel<<<1, 128, 0, stream>>>(scores, qid, out);
}

// Round 2
// 504.603 us; speedup vs baseline: 1.6496x; 1.6496x over previous
//
#include <hip/hip_runtime.h>
#include <hip/hip_bf16.h>
#include <math.h>

#define NB 128   // batch
#define NR 36    // regions
#define NW 32    // words
#define ND 256   // feature dim

#define MARGINf 0.05f
#define TEMPf   14.0f
#define LAMf    9.0f
#define EPSf    1e-8f

typedef _Float16 f16x8 __attribute__((ext_vector_type(8)));
typedef float    f32x4 __attribute__((ext_vector_type(4)));

// workspace layout (float offsets)
#define G_STRIDE  40
#define WS_SCORES 0
#define WS_G      (NB * NB)                       // 16384
#define WS_N1     (WS_G + NB * NR * G_STRIDE)     // + 184320

// f16 LDS row stride (halves): 256 + 8 keeps 16B alignment, spreads banks
#define HS 264

// ---------------- prep: per-image Gram + per-caption word norms ----------------
__global__ __launch_bounds__(256) void prep_kernel(
    const float* __restrict__ im, const float* __restrict__ s,
    float* __restrict__ ws)
{
    const int b = blockIdx.x;
    const int t = threadIdx.x;
    __shared__ float s_imf[NR * 260];

    const float4* im4 = (const float4*)(im + (size_t)b * NR * ND);
    for (int i = t; i < NR * (ND / 4); i += 256) {
        int r = i >> 6, c4 = i & 63;
        *(float4*)&s_imf[r * 260 + 4 * c4] = im4[i];
    }
    __syncthreads();

    float* G = ws + WS_G + (size_t)b * NR * G_STRIDE;
    for (int i = t; i < NR * NR; i += 256) {
        int r = i / NR, rp = i - r * NR;
        const float4* a  = (const float4*)&s_imf[r * 260];
        const float4* bb = (const float4*)&s_imf[rp * 260];
        float acc = 0.f;
        for (int k = 0; k < ND / 4; ++k) {
            float4 x = a[k], y = bb[k];
            acc += x.x * y.x + x.y * y.y + x.z * y.z + x.w * y.w;
        }
        G[r * G_STRIDE + rp] = acc;
    }

    // caption word norms n1[b][w]
    const int w = t >> 3, g = t & 7;
    const float4* s4 = (const float4*)(s + (size_t)b * NW * ND);
    float acc = 0.f;
    for (int j = 0; j < 8; ++j) {
        float4 v = s4[w * 64 + g * 8 + j];
        acc += v.x * v.x + v.y * v.y + v.z * v.z + v.w * v.w;
    }
    acc += __shfl_down(acc, 4, 8);
    acc += __shfl_down(acc, 2, 8);
    acc += __shfl_down(acc, 1, 8);
    if (g == 0) ws[WS_N1 + b * NW + w] = sqrtf(acc);
}

// ---------------- per-pair scores: MFMA dots + glue ----------------
__global__ __launch_bounds__(384) void scores_kernel(
    const float* __restrict__ im, const float* __restrict__ s,
    const int* __restrict__ s_l, const float* __restrict__ im_mask,
    float* __restrict__ ws)
{
    const int c = blockIdx.x;   // caption
    const int b = blockIdx.y;   // image
    const int t = threadIdx.x;

    __shared__ _Float16 s_imh[48 * HS];     // rows 36..47 zero pad
    __shared__ _Float16 s_caph[NW * HS];
    __shared__ float s_A0[NR * 33];         // raw dots
    __shared__ float s_X[NR * 33];          // leaky + (1-m)
    __shared__ float s_y[NW * 40];          // softmax weights y[w][r]
    __shared__ float s_G[NR * G_STRIDE];
    __shared__ float s_nrm[NR];
    __shared__ float s_m[NR];
    __shared__ float s_p1[NW * 12];
    __shared__ float s_p2[NW * 12];

    const int sl = s_l[c];

    // stage im[b] -> f16 (8-float chunks)
    const float4* im4 = (const float4*)(im + (size_t)b * NR * ND);
    for (int i = t; i < NR * 32; i += 384) {
        int r = i >> 5, ch = i & 31;
        float4 a  = im4[r * 64 + ch * 2];
        float4 bb = im4[r * 64 + ch * 2 + 1];
        f16x8 h;
        h[0] = (_Float16)a.x;  h[1] = (_Float16)a.y;
        h[2] = (_Float16)a.z;  h[3] = (_Float16)a.w;
        h[4] = (_Float16)bb.x; h[5] = (_Float16)bb.y;
        h[6] = (_Float16)bb.z; h[7] = (_Float16)bb.w;
        *(f16x8*)&s_imh[r * HS + ch * 8] = h;
    }
    // zero pad rows 36..47
    {
        unsigned int* z = (unsigned int*)&s_imh[NR * HS];
        for (int i = t; i < 12 * (HS / 2); i += 384) z[i] = 0u;
    }
    // stage cap[c] (word-masked) -> f16
    const float4* s4 = (const float4*)(s + (size_t)c * NW * ND);
    for (int i = t; i < NW * 32; i += 384) {
        int w = i >> 5, ch = i & 31;
        f16x8 h;
        if (w < sl) {
            float4 a  = s4[w * 64 + ch * 2];
            float4 bb = s4[w * 64 + ch * 2 + 1];
            h[0] = (_Float16)a.x;  h[1] = (_Float16)a.y;
            h[2] = (_Float16)a.z;  h[3] = (_Float16)a.w;
            h[4] = (_Float16)bb.x; h[5] = (_Float16)bb.y;
            h[6] = (_Float16)bb.z; h[7] = (_Float16)bb.w;
        } else {
#pragma unroll
            for (int k = 0; k < 8; ++k) h[k] = (_Float16)0.f;
        }
        *(f16x8*)&s_caph[w * HS + ch * 8] = h;
    }
    // stage Gram (float4 rows, stride 40)
    {
        const float4* Gg = (const float4*)(ws + WS_G + (size_t)b * NR * G_STRIDE);
        float4* Gs = (float4*)s_G;
        for (int i = t; i < NR * 9; i += 384) {
            int r = i / 9, q = i - r * 9;
            Gs[r * 10 + q] = Gg[r * 10 + q];
        }
    }
    if (t < NR) s_m[t] = im_mask[b * NR + t];
    __syncthreads();

    // ---- MFMA: A0[r][w] = im[r] . cap[w], 48x32 padded, K=256 ----
    {
        const int wave = t >> 6, lane = t & 63;
        const int r0 = (wave >> 1) * 16, w0 = (wave & 1) * 16;
        const int m = lane & 15, kg = lane >> 4;
        f32x4 acc = {0.f, 0.f, 0.f, 0.f};
        const _Float16* ap = &s_imh[(r0 + m) * HS + kg * 8];
        const _Float16* bp = &s_caph[(w0 + m) * HS + kg * 8];
#pragma unroll
        for (int ks = 0; ks < 8; ++ks) {
            f16x8 av = *(const f16x8*)(ap + ks * 32);
            f16x8 bv = *(const f16x8*)(bp + ks * 32);
            acc = __builtin_amdgcn_mfma_f32_16x16x32_f16(av, bv, acc, 0, 0, 0);
        }
        // C layout: row=(lane>>4)*4+v, col=lane&15
        const int wcol = w0 + m;
        const int rbase = r0 + kg * 4;
#pragma unroll
        for (int v = 0; v < 4; ++v) {
            int r = rbase + v;
            if (r < NR) {
                float raw = acc[v];
                s_A0[r * 33 + wcol] = raw;
                float lk = raw >= 0.f ? raw : 0.1f * raw;
                s_X[r * 33 + wcol] = lk + (1.f - s_m[r]);
            }
        }
    }
    __syncthreads();

    // ---- nrm[r] = sqrt(sum_w X^2) + EPS ----
    if (t < NR) {
        float sum = 0.f;
        for (int w = 0; w < NW; ++w) { float x = s_X[t * 33 + w]; sum += x * x; }
        s_nrm[t] = sqrtf(sum) + EPSf;
    }
    __syncthreads();

    // ---- softmax over r per word ----
    if (t < NW) {
        float xs[NR];
        float mx = -1e30f;
#pragma unroll
        for (int r = 0; r < NR; ++r) {
            float a = s_X[r * 33 + t] / s_nrm[r] * s_m[r] * LAMf;
            xs[r] = a; mx = fmaxf(mx, a);
        }
        float sum = 0.f;
#pragma unroll
        for (int r = 0; r < NR; ++r) {
            float e = __expf(xs[r] - mx) * s_m[r];
            xs[r] = e; sum += e;
        }
        float inv = 1.f / sum;
#pragma unroll
        for (int r = 0; r < NR; ++r) s_y[t * 40 + r] = xs[r] * inv;
    }
    __syncthreads();

    // ---- w12[w] = sum_r y.A0 ; n2^2[w] = y G y^T ----
    if (t < 288) {
        const int w = t / 9, q = t - (t / 9) * 9;   // q indexes 4-wide r' quads
        float4 y4 = *(const float4*)&s_y[w * 40 + q * 4];
        float4 acc4 = {0.f, 0.f, 0.f, 0.f};
        float w12p = 0.f;
#pragma unroll
        for (int r = 0; r < NR; ++r) {
            float yr = s_y[w * 40 + r];
            float4 g4 = *(const float4*)&s_G[r * G_STRIDE + q * 4];
            acc4.x += yr * g4.x; acc4.y += yr * g4.y;
            acc4.z += yr * g4.z; acc4.w += yr * g4.w;
        }
        float n2p = acc4.x * y4.x + acc4.y * y4.y + acc4.z * y4.z + acc4.w * y4.w;
#pragma unroll
        for (int k = 0; k < 4; ++k) {
            int r = q * 4 + k;
            w12p += s_y[w * 40 + r] * s_A0[r * 33 + w];
        }
        s_p1[w * 12 + q] = w12p;
        s_p2[w * 12 + q] = n2p;
    }
    __syncthreads();

    // ---- cos, masked mean ----
    if (t < NW) {
        float w12v = 0.f, n2v = 0.f;
        for (int q = 0; q < 9; ++q) { w12v += s_p1[t * 12 + q]; n2v += s_p2[t * 12 + q]; }
        float n1v = ws[WS_N1 + c * NW + t];
        float cosv = w12v / fmaxf(n1v * sqrtf(n2v), EPSf);
        float val = (t < sl) ? cosv : 0.f;
#pragma unroll
        for (int k = 16; k; k >>= 1) val += __shfl_down(val, k, 32);
        if (t == 0) ws[WS_SCORES + b * NB + c] = val / (float)sl;
    }
}

// ---------------- contrastive loss over 128x128 scores ----------------
__global__ __launch_bounds__(128) void loss_kernel(
    const float* __restrict__ scores, const int* __restrict__ qid,
    float* __restrict__ out)
{
    __shared__ int   s_q[NB];
    __shared__ float s_c[NB];
    __shared__ float s_v[NB];
    const int i = threadIdx.x;
    s_q[i] = qid[i];
    __syncthreads();

    const int q = s_q[i];
    bool dup = false;
    for (int j = 0; j < i; ++j) dup = dup || (s_q[j] == q);

    const float* row = scores + i * NB;
    float mx = -1e30f;
    for (int j = 0; j < NB; ++j) {
        float l = (row[j] - ((j == i) ? MARGINf : 0.f)) * TEMPf;
        mx = fmaxf(mx, l);
    }
    float sum = 0.f;
    for (int j = 0; j < NB; ++j) {
        float l = (row[j] - ((j == i) ? MARGINf : 0.f)) * TEMPf;
        sum += expf(l - mx);
    }
    const float logZ = mx + logf(sum);
    const float picked = (row[i] - MARGINf) * TEMPf;
    const float valid = dup ? 0.f : 1.f;
    s_c[i] = (logZ - picked) * valid;
    s_v[i] = valid;
    __syncthreads();
    if (i == 0) {
        float a = 0.f, v = 0.f;
        for (int j = 0; j < NB; ++j) { a += s_c[j]; v += s_v[j]; }
        out[0] = a / fmaxf(v, 1.f);
    }
}

extern "C" void kernel_launch(void* const* d_in, const int* in_sizes, int n_in,
                              void* d_out, int out_size, void* d_ws, size_t ws_size,
                              hipStream_t stream) {
    const float* im      = (const float*)d_in[0];
    const float* s       = (const float*)d_in[1];
    const int*   s_l     = (const int*)d_in[2];
    const float* im_mask = (const float*)d_in[3];
    const int*   qid     = (const int*)d_in[4];

    float* ws  = (float*)d_ws;
    float* out = (float*)d_out;

    prep_kernel<<<NB, 256, 0, stream>>>(im, s, ws);
    dim3 grid(NB, NB);
    scores_kernel<<<grid, 384, 0, stream>>>(im, s, s_l, im_mask, ws);
    loss_kernel<<<1, 128, 0, stream>>>(ws + WS_SCORES, qid, out);
}

// Round 3
// 208.900 us; speedup vs baseline: 3.9847x; 2.4155x over previous
//
#include <hip/hip_runtime.h>
#include <hip/hip_bf16.h>
#include <math.h>

#define NB 128   // batch
#define NR 36    // regions
#define NW 32    // words
#define ND 256   // feature dim

#define MARGINf 0.05f
#define TEMPf   14.0f
#define LAMf    9.0f
#define EPSf    1e-8f

typedef _Float16 f16x8 __attribute__((ext_vector_type(8)));
typedef _Float16 f16x4 __attribute__((ext_vector_type(4)));
typedef float    f32x4 __attribute__((ext_vector_type(4)));

// ================= new-path workspace layout (float offsets) =================
#define WS_SCORES 0
#define WS_N1     16384
#define WS_GH     20480                 // f16[128][48*68]
#define GH_ELEMS  (48 * 68)             // 3264 f16 per image
#define WS_A0     229376                // f16[4096][4608]  (row = c*32+w, col = b*36+r)
#define LDA0      4608
#define WS_NEED_BYTES ((size_t)(229376 + 9437184) * 4)   // 38,666,240 B

// ================= fallback (R2) workspace layout =================
#define G_STRIDE  40
#define FB_WS_G   (NB * NB)
#define FB_WS_N1  (FB_WS_G + NB * NR * G_STRIDE)
#define HS 264

// =====================================================================
// NEW PATH
// =====================================================================

// ---- prep: per-image Gram (f16, padded 48x68) + per-caption word norms ----
__global__ __launch_bounds__(256) void prep2_kernel(
    const float* __restrict__ im, const float* __restrict__ s,
    float* __restrict__ ws)
{
    const int b = blockIdx.x;
    const int t = threadIdx.x;
    __shared__ float s_imf[NR * 260];

    const float4* im4 = (const float4*)(im + (size_t)b * NR * ND);
    for (int i = t; i < NR * 64; i += 256) {
        int r = i >> 6, c4 = i & 63;
        *(float4*)&s_imf[r * 260 + 4 * c4] = im4[i];
    }
    _Float16* Gh = (_Float16*)(ws + WS_GH) + (size_t)b * GH_ELEMS;
    for (int i = t; i < GH_ELEMS / 2; i += 256) ((unsigned int*)Gh)[i] = 0u;
    __syncthreads();

    for (int i = t; i < NR * NR; i += 256) {
        int r = i / NR, rp = i - r * NR;
        const float4* a  = (const float4*)&s_imf[r * 260];
        const float4* bb = (const float4*)&s_imf[rp * 260];
        float acc = 0.f;
        for (int k = 0; k < 64; ++k) {
            float4 x = a[k], y = bb[k];
            acc += x.x * y.x + x.y * y.y + x.z * y.z + x.w * y.w;
        }
        Gh[r * 68 + rp] = (_Float16)acc;
    }

    const int w = t >> 3, g = t & 7;
    const float4* s4 = (const float4*)(s + (size_t)b * NW * ND);
    float acc = 0.f;
    for (int j = 0; j < 8; ++j) {
        float4 v = s4[w * 64 + g * 8 + j];
        acc += v.x * v.x + v.y * v.y + v.z * v.z + v.w * v.w;
    }
    acc += __shfl_down(acc, 4, 8);
    acc += __shfl_down(acc, 2, 8);
    acc += __shfl_down(acc, 1, 8);
    if (g == 0) ws[WS_N1 + b * NW + w] = sqrtf(acc);
}

// ---- GEMM: A0t[n][m] = cap[n] . im[m]  (f16 out, transposed store) ----
#define KHS 136
__global__ __launch_bounds__(512) void gemm_kernel(
    const float* __restrict__ im, const float* __restrict__ s,
    const int* __restrict__ s_l, float* __restrict__ ws)
{
    const int n0 = blockIdx.x * 128;   // caption-word rows
    const int m0 = blockIdx.y * 128;   // image-region rows
    const int t = threadIdx.x;
    __shared__ _Float16 sA[128 * KHS];
    __shared__ _Float16 sB[128 * KHS];

    const int i = t >> 2, q = t & 3;
    const int brow = n0 + i;
    const int slr = s_l[brow >> 5];
    const bool bz = ((brow & 31) >= slr);

    const int wave = t >> 6, lane = t & 63;
    const int mts = (wave & 3) * 2;
    const int nts = (wave >> 2) * 4;
    const int lm = lane & 15, kg = lane >> 4;

    f32x4 acc[2][4];
#pragma unroll
    for (int a_ = 0; a_ < 2; ++a_)
#pragma unroll
        for (int bn = 0; bn < 4; ++bn) acc[a_][bn] = (f32x4){0.f, 0.f, 0.f, 0.f};

    const float4* Ag = (const float4*)(im + (size_t)(m0 + i) * ND);
    const float4* Bg = (const float4*)(s + (size_t)brow * ND);

    for (int kk = 0; kk < 2; ++kk) {
#pragma unroll
        for (int j = 0; j < 8; ++j) {
            float4 av = Ag[kk * 32 + q + 4 * j];
            f16x4 ah;
            ah[0] = (_Float16)av.x; ah[1] = (_Float16)av.y;
            ah[2] = (_Float16)av.z; ah[3] = (_Float16)av.w;
            *(f16x4*)&sA[i * KHS + (q + 4 * j) * 4] = ah;
            f16x4 bh;
            if (bz) {
                bh[0] = bh[1] = bh[2] = bh[3] = (_Float16)0.f;
            } else {
                float4 bv = Bg[kk * 32 + q + 4 * j];
                bh[0] = (_Float16)bv.x; bh[1] = (_Float16)bv.y;
                bh[2] = (_Float16)bv.z; bh[3] = (_Float16)bv.w;
            }
            *(f16x4*)&sB[i * KHS + (q + 4 * j) * 4] = bh;
        }
        __syncthreads();
#pragma unroll
        for (int ks = 0; ks < 4; ++ks) {
            f16x8 af[2], bf[4];
#pragma unroll
            for (int mi = 0; mi < 2; ++mi)
                af[mi] = *(const f16x8*)&sA[((mts + mi) * 16 + lm) * KHS + ks * 32 + kg * 8];
#pragma unroll
            for (int ni = 0; ni < 4; ++ni)
                bf[ni] = *(const f16x8*)&sB[((nts + ni) * 16 + lm) * KHS + ks * 32 + kg * 8];
#pragma unroll
            for (int mi = 0; mi < 2; ++mi)
#pragma unroll
                for (int ni = 0; ni < 4; ++ni)
                    acc[mi][ni] = __builtin_amdgcn_mfma_f32_16x16x32_f16(af[mi], bf[ni], acc[mi][ni], 0, 0, 0);
        }
        __syncthreads();
    }

    _Float16* A0 = (_Float16*)(ws + WS_A0);
#pragma unroll
    for (int mi = 0; mi < 2; ++mi)
#pragma unroll
        for (int ni = 0; ni < 4; ++ni) {
            const int n = n0 + (nts + ni) * 16 + lm;
            const int m = m0 + (mts + mi) * 16 + kg * 4;
            f16x4 h;
            h[0] = (_Float16)acc[mi][ni][0];
            h[1] = (_Float16)acc[mi][ni][1];
            h[2] = (_Float16)acc[mi][ni][2];
            h[3] = (_Float16)acc[mi][ni][3];
            *(f16x4*)(A0 + (size_t)n * LDA0 + m) = h;
        }
}

// ---- glue: per (image b, 8 captions): softmax pipeline + Y*G MFMA ----
__global__ __launch_bounds__(256) void glue_kernel(
    const int* __restrict__ s_l, const float* __restrict__ im_mask,
    float* __restrict__ ws)
{
    const int c0 = blockIdx.x * 8;
    const int b  = blockIdx.y;
    const int t  = threadIdx.x;

    __shared__ _Float16 s_G[48 * 68];
    __shared__ _Float16 s_Y[8][32 * 68];
    __shared__ float s_w12[8][32];
    __shared__ float s_n1f[8][32];
    __shared__ float s_m[NR];
    __shared__ int   s_sl[8];

    const _Float16* Gh = (const _Float16*)(ws + WS_GH) + (size_t)b * GH_ELEMS;
    for (int idx = t; idx < GH_ELEMS / 2; idx += 256)
        ((unsigned int*)s_G)[idx] = ((const unsigned int*)Gh)[idx];
    if (t < NR) s_m[t] = im_mask[b * NR + t];
    if (t < 8)  s_sl[t] = s_l[c0 + t];
    {
        const int p = t >> 5, w = t & 31;
        s_n1f[p][w] = ws[WS_N1 + (c0 + p) * NW + w];
    }
    __syncthreads();

    // ---------- phase 1: per (pair, word) column pipeline ----------
    {
        const int p = t >> 5, w = t & 31;
        const int cc = c0 + p;
        const _Float16* arow = (const _Float16*)(ws + WS_A0) + (size_t)(cc * 32 + w) * LDA0 + b * NR;
        float raw[NR];
#pragma unroll
        for (int j = 0; j < 9; ++j) {
            f16x4 h = *(const f16x4*)(arow + 4 * j);
            raw[4 * j + 0] = (float)h[0];
            raw[4 * j + 1] = (float)h[1];
            raw[4 * j + 2] = (float)h[2];
            raw[4 * j + 3] = (float)h[3];
        }
        float nr2[NR];
#pragma unroll
        for (int r = 0; r < NR; ++r) {
            float X = (raw[r] >= 0.f ? raw[r] : 0.1f * raw[r]) + (1.f - s_m[r]);
            nr2[r] = X * X;
        }
#pragma unroll
        for (int r = 0; r < NR; ++r) {
            float v = nr2[r];
            v += __shfl_xor(v, 1, 32);
            v += __shfl_xor(v, 2, 32);
            v += __shfl_xor(v, 4, 32);
            v += __shfl_xor(v, 8, 32);
            v += __shfl_xor(v, 16, 32);
            nr2[r] = v;
        }
        float a_[NR];
        float mx = -1e30f;
#pragma unroll
        for (int r = 0; r < NR; ++r) {
            float X = (raw[r] >= 0.f ? raw[r] : 0.1f * raw[r]) + (1.f - s_m[r]);
            float nrm = sqrtf(nr2[r]) + EPSf;
            float aa = X / nrm * s_m[r] * LAMf;
            a_[r] = aa; mx = fmaxf(mx, aa);
        }
        float sum = 0.f;
#pragma unroll
        for (int r = 0; r < NR; ++r) {
            float e = __expf(a_[r] - mx) * s_m[r];
            a_[r] = e; sum += e;
        }
        const float inv = 1.f / sum;
        float w12 = 0.f;
#pragma unroll
        for (int r = 0; r < NR; ++r) {
            float y = a_[r] * inv;
            a_[r] = y;
            w12 += y * raw[r];
        }
        s_w12[p][w] = w12;
        _Float16* yrow = &s_Y[p][w * 68];
#pragma unroll
        for (int j = 0; j < 9; ++j) {
            f16x4 h;
            h[0] = (_Float16)a_[4 * j + 0];
            h[1] = (_Float16)a_[4 * j + 1];
            h[2] = (_Float16)a_[4 * j + 2];
            h[3] = (_Float16)a_[4 * j + 3];
            *(f16x4*)(yrow + 4 * j) = h;
        }
        f16x4 z4; z4[0] = z4[1] = z4[2] = z4[3] = (_Float16)0.f;
#pragma unroll
        for (int j = 9; j < 16; ++j) *(f16x4*)(yrow + 4 * j) = z4;
    }
    __syncthreads();

    // ---------- phase 2: n2 via Z = Y*G MFMA, then cos + score ----------
    {
        const int wave = t >> 6, lane = t & 63;
        const int lm = lane & 15, kg = lane >> 4;
        for (int round = 0; round < 2; ++round) {
            const int pp = wave + 4 * round;
            const int ccc = c0 + pp;
            f32x4 zacc[2][3];
#pragma unroll
            for (int mi = 0; mi < 2; ++mi)
#pragma unroll
                for (int ni = 0; ni < 3; ++ni) zacc[mi][ni] = (f32x4){0.f, 0.f, 0.f, 0.f};
#pragma unroll
            for (int ks = 0; ks < 2; ++ks) {
                f16x8 yf[2], gf[3];
#pragma unroll
                for (int mi = 0; mi < 2; ++mi)
                    yf[mi] = *(const f16x8*)&s_Y[pp][(mi * 16 + lm) * 68 + ks * 32 + kg * 8];
#pragma unroll
                for (int ni = 0; ni < 3; ++ni)
                    gf[ni] = *(const f16x8*)&s_G[(ni * 16 + lm) * 68 + ks * 32 + kg * 8];
#pragma unroll
                for (int mi = 0; mi < 2; ++mi)
#pragma unroll
                    for (int ni = 0; ni < 3; ++ni)
                        zacc[mi][ni] = __builtin_amdgcn_mfma_f32_16x16x32_f16(yf[mi], gf[ni], zacc[mi][ni], 0, 0, 0);
            }
            float part = 0.f;
            const int slp = s_sl[pp];
#pragma unroll
            for (int mi = 0; mi < 2; ++mi)
#pragma unroll
                for (int vi = 0; vi < 4; ++vi) {
                    const int ww = mi * 16 + kg * 4 + vi;
                    float v = 0.f;
#pragma unroll
                    for (int ni = 0; ni < 3; ++ni) {
                        const int rp = ni * 16 + lm;
                        v += zacc[mi][ni][vi] * (float)s_Y[pp][ww * 68 + rp];
                    }
                    v += __shfl_xor(v, 1, 16);
                    v += __shfl_xor(v, 2, 16);
                    v += __shfl_xor(v, 4, 16);
                    v += __shfl_xor(v, 8, 16);
                    if (lm == 0) {
                        const float n2 = fmaxf(v, 0.f);
                        const float cosv = s_w12[pp][ww] / fmaxf(s_n1f[pp][ww] * sqrtf(n2), EPSf);
                        part += (ww < slp) ? cosv : 0.f;
                    }
                }
            part += __shfl_xor(part, 16);
            part += __shfl_xor(part, 32);
            if (lane == 0) ws[WS_SCORES + b * NB + ccc] = part / (float)slp;
        }
    }
}

// =====================================================================
// FALLBACK PATH (R2, used only if ws_size too small)
// =====================================================================
__global__ __launch_bounds__(256) void prep_fb_kernel(
    const float* __restrict__ im, const float* __restrict__ s,
    float* __restrict__ ws)
{
    const int b = blockIdx.x;
    const int t = threadIdx.x;
    __shared__ float s_imf[NR * 260];

    const float4* im4 = (const float4*)(im + (size_t)b * NR * ND);
    for (int i = t; i < NR * (ND / 4); i += 256) {
        int r = i >> 6, c4 = i & 63;
        *(float4*)&s_imf[r * 260 + 4 * c4] = im4[i];
    }
    __syncthreads();

    float* G = ws + FB_WS_G + (size_t)b * NR * G_STRIDE;
    for (int i = t; i < NR * NR; i += 256) {
        int r = i / NR, rp = i - r * NR;
        const float4* a  = (const float4*)&s_imf[r * 260];
        const float4* bb = (const float4*)&s_imf[rp * 260];
        float acc = 0.f;
        for (int k = 0; k < ND / 4; ++k) {
            float4 x = a[k], y = bb[k];
            acc += x.x * y.x + x.y * y.y + x.z * y.z + x.w * y.w;
        }
        G[r * G_STRIDE + rp] = acc;
    }

    const int w = t >> 3, g = t & 7;
    const float4* s4 = (const float4*)(s + (size_t)b * NW * ND);
    float acc = 0.f;
    for (int j = 0; j < 8; ++j) {
        float4 v = s4[w * 64 + g * 8 + j];
        acc += v.x * v.x + v.y * v.y + v.z * v.z + v.w * v.w;
    }
    acc += __shfl_down(acc, 4, 8);
    acc += __shfl_down(acc, 2, 8);
    acc += __shfl_down(acc, 1, 8);
    if (g == 0) ws[FB_WS_N1 + b * NW + w] = sqrtf(acc);
}

__global__ __launch_bounds__(384) void scores_fb_kernel(
    const float* __restrict__ im, const float* __restrict__ s,
    const int* __restrict__ s_l, const float* __restrict__ im_mask,
    float* __restrict__ ws)
{
    const int c = blockIdx.x;
    const int b = blockIdx.y;
    const int t = threadIdx.x;

    __shared__ _Float16 s_imh[48 * HS];
    __shared__ _Float16 s_caph[NW * HS];
    __shared__ float s_A0[NR * 33];
    __shared__ float s_X[NR * 33];
    __shared__ float s_y[NW * 40];
    __shared__ float s_Gf[NR * G_STRIDE];
    __shared__ float s_nrm[NR];
    __shared__ float s_m[NR];
    __shared__ float s_p1[NW * 12];
    __shared__ float s_p2[NW * 12];

    const int sl = s_l[c];

    const float4* im4 = (const float4*)(im + (size_t)b * NR * ND);
    for (int i = t; i < NR * 32; i += 384) {
        int r = i >> 5, ch = i & 31;
        float4 a  = im4[r * 64 + ch * 2];
        float4 bb = im4[r * 64 + ch * 2 + 1];
        f16x8 h;
        h[0] = (_Float16)a.x;  h[1] = (_Float16)a.y;
        h[2] = (_Float16)a.z;  h[3] = (_Float16)a.w;
        h[4] = (_Float16)bb.x; h[5] = (_Float16)bb.y;
        h[6] = (_Float16)bb.z; h[7] = (_Float16)bb.w;
        *(f16x8*)&s_imh[r * HS + ch * 8] = h;
    }
    {
        unsigned int* z = (unsigned int*)&s_imh[NR * HS];
        for (int i = t; i < 12 * (HS / 2); i += 384) z[i] = 0u;
    }
    const float4* s4 = (const float4*)(s + (size_t)c * NW * ND);
    for (int i = t; i < NW * 32; i += 384) {
        int w = i >> 5, ch = i & 31;
        f16x8 h;
        if (w < sl) {
            float4 a  = s4[w * 64 + ch * 2];
            float4 bb = s4[w * 64 + ch * 2 + 1];
            h[0] = (_Float16)a.x;  h[1] = (_Float16)a.y;
            h[2] = (_Float16)a.z;  h[3] = (_Float16)a.w;
            h[4] = (_Float16)bb.x; h[5] = (_Float16)bb.y;
            h[6] = (_Float16)bb.z; h[7] = (_Float16)bb.w;
        } else {
#pragma unroll
            for (int k = 0; k < 8; ++k) h[k] = (_Float16)0.f;
        }
        *(f16x8*)&s_caph[w * HS + ch * 8] = h;
    }
    {
        const float4* Gg = (const float4*)(ws + FB_WS_G + (size_t)b * NR * G_STRIDE);
        float4* Gs = (float4*)s_Gf;
        for (int i = t; i < NR * 9; i += 384) {
            int r = i / 9, q = i - r * 9;
            Gs[r * 10 + q] = Gg[r * 10 + q];
        }
    }
    if (t < NR) s_m[t] = im_mask[b * NR + t];
    __syncthreads();

    {
        const int wave = t >> 6, lane = t & 63;
        const int r0 = (wave >> 1) * 16, w0 = (wave & 1) * 16;
        const int m = lane & 15, kg = lane >> 4;
        f32x4 acc = {0.f, 0.f, 0.f, 0.f};
        const _Float16* ap = &s_imh[(r0 + m) * HS + kg * 8];
        const _Float16* bp = &s_caph[(w0 + m) * HS + kg * 8];
#pragma unroll
        for (int ks = 0; ks < 8; ++ks) {
            f16x8 av = *(const f16x8*)(ap + ks * 32);
            f16x8 bv = *(const f16x8*)(bp + ks * 32);
            acc = __builtin_amdgcn_mfma_f32_16x16x32_f16(av, bv, acc, 0, 0, 0);
        }
        const int wcol = w0 + m;
        const int rbase = r0 + kg * 4;
#pragma unroll
        for (int v = 0; v < 4; ++v) {
            int r = rbase + v;
            if (r < NR) {
                float rawv = acc[v];
                s_A0[r * 33 + wcol] = rawv;
                float lk = rawv >= 0.f ? rawv : 0.1f * rawv;
                s_X[r * 33 + wcol] = lk + (1.f - s_m[r]);
            }
        }
    }
    __syncthreads();

    if (t < NR) {
        float sum = 0.f;
        for (int w = 0; w < NW; ++w) { float x = s_X[t * 33 + w]; sum += x * x; }
        s_nrm[t] = sqrtf(sum) + EPSf;
    }
    __syncthreads();

    if (t < NW) {
        float xs[NR];
        float mx = -1e30f;
#pragma unroll
        for (int r = 0; r < NR; ++r) {
            float a = s_X[r * 33 + t] / s_nrm[r] * s_m[r] * LAMf;
            xs[r] = a; mx = fmaxf(mx, a);
        }
        float sum = 0.f;
#pragma unroll
        for (int r = 0; r < NR; ++r) {
            float e = __expf(xs[r] - mx) * s_m[r];
            xs[r] = e; sum += e;
        }
        float inv = 1.f / sum;
#pragma unroll
        for (int r = 0; r < NR; ++r) s_y[t * 40 + r] = xs[r] * inv;
    }
    __syncthreads();

    if (t < 288) {
        const int w = t / 9, q = t - (t / 9) * 9;
        float4 y4 = *(const float4*)&s_y[w * 40 + q * 4];
        float4 acc4 = {0.f, 0.f, 0.f, 0.f};
        float w12p = 0.f;
#pragma unroll
        for (int r = 0; r < NR; ++r) {
            float yr = s_y[w * 40 + r];
            float4 g4 = *(const float4*)&s_Gf[r * G_STRIDE + q * 4];
            acc4.x += yr * g4.x; acc4.y += yr * g4.y;
            acc4.z += yr * g4.z; acc4.w += yr * g4.w;
        }
        float n2p = acc4.x * y4.x + acc4.y * y4.y + acc4.z * y4.z + acc4.w * y4.w;
#pragma unroll
        for (int k = 0; k < 4; ++k) {
            int r = q * 4 + k;
            w12p += s_y[w * 40 + r] * s_A0[r * 33 + w];
        }
        s_p1[w * 12 + q] = w12p;
        s_p2[w * 12 + q] = n2p;
    }
    __syncthreads();

    if (t < NW) {
        float w12v = 0.f, n2v = 0.f;
        for (int q = 0; q < 9; ++q) { w12v += s_p1[t * 12 + q]; n2v += s_p2[t * 12 + q]; }
        float n1v = ws[FB_WS_N1 + c * NW + t];
        float cosv = w12v / fmaxf(n1v * sqrtf(n2v), EPSf);
        float val = (t < sl) ? cosv : 0.f;
#pragma unroll
        for (int k = 16; k; k >>= 1) val += __shfl_down(val, k, 32);
        if (t == 0) ws[WS_SCORES + b * NB + c] = val / (float)sl;
    }
}

// ---------------- contrastive loss over 128x128 scores ----------------
__global__ __launch_bounds__(128) void loss_kernel(
    const float* __restrict__ scores, const int* __restrict__ qid,
    float* __restrict__ out)
{
    __shared__ int   s_q[NB];
    __shared__ float s_c[NB];
    __shared__ float s_v[NB];
    const int i = threadIdx.x;
    s_q[i] = qid[i];
    __syncthreads();

    const int q = s_q[i];
    bool dup = false;
    for (int j = 0; j < i; ++j) dup = dup || (s_q[j] == q);

    const float* row = scores + i * NB;
    float mx = -1e30f;
    for (int j = 0; j < NB; ++j) {
        float l = (row[j] - ((j == i) ? MARGINf : 0.f)) * TEMPf;
        mx = fmaxf(mx, l);
    }
    float sum = 0.f;
    for (int j = 0; j < NB; ++j) {
        float l = (row[j] - ((j == i) ? MARGINf : 0.f)) * TEMPf;
        sum += expf(l - mx);
    }
    const float logZ = mx + logf(sum);
    const float picked = (row[i] - MARGINf) * TEMPf;
    const float valid = dup ? 0.f : 1.f;
    s_c[i] = (logZ - picked) * valid;
    s_v[i] = valid;
    __syncthreads();
    if (i == 0) {
        float a = 0.f, v = 0.f;
        for (int j = 0; j < NB; ++j) { a += s_c[j]; v += s_v[j]; }
        out[0] = a / fmaxf(v, 1.f);
    }
}

extern "C" void kernel_launch(void* const* d_in, const int* in_sizes, int n_in,
                              void* d_out, int out_size, void* d_ws, size_t ws_size,
                              hipStream_t stream) {
    const float* im      = (const float*)d_in[0];
    const float* s       = (const float*)d_in[1];
    const int*   s_l     = (const int*)d_in[2];
    const float* im_mask = (const float*)d_in[3];
    const int*   qid     = (const int*)d_in[4];

    float* ws  = (float*)d_ws;
    float* out = (float*)d_out;

    if (ws_size >= WS_NEED_BYTES) {
        prep2_kernel<<<NB, 256, 0, stream>>>(im, s, ws);
        gemm_kernel<<<dim3(32, 36), 512, 0, stream>>>(im, s, s_l, ws);
        glue_kernel<<<dim3(16, NB), 256, 0, stream>>>(s_l, im_mask, ws);
    } else {
        prep_fb_kernel<<<NB, 256, 0, stream>>>(im, s, ws);
        dim3 grid(NB, NB);
        scores_fb_kernel<<<grid, 384, 0, stream>>>(im, s, s_l, im_mask, ws);
    }
    loss_kernel<<<1, 128, 0, stream>>>(ws + WS_SCORES, qid, out);
}

// Round 4
// 202.386 us; speedup vs baseline: 4.1130x; 1.0322x over previous
//
#include <hip/hip_runtime.h>
#include <hip/hip_bf16.h>
#include <math.h>

#define NB 128   // batch
#define NR 36    // regions
#define NW 32    // words
#define ND 256   // feature dim

#define MARGINf 0.05f
#define TEMPf   14.0f
#define LAMf    9.0f
#define EPSf    1e-8f

typedef _Float16 f16x8 __attribute__((ext_vector_type(8)));
typedef _Float16 f16x4 __attribute__((ext_vector_type(4)));
typedef float    f32x4 __attribute__((ext_vector_type(4)));

// ================= new-path workspace layout (float offsets) =================
// byte-identical footprint to round-3 layout (proven to fit in d_ws)
#define WS_SCORES 0
#define WS_N1     16384
#define WS_GH     20480                 // f16[128][48*68]
#define GH_ELEMS  (48 * 68)             // 3264 f16 per image
#define WS_A0     229376                // f16[4608][4096]  (row m = b*36+r, col n = c*32+w)
#define LDA0      4096
#define WS_NEED_BYTES ((size_t)(229376 + 9437184) * 4)   // 38,666,240 B

// ================= fallback (R2) workspace layout =================
#define G_STRIDE  40
#define FB_WS_G   (NB * NB)
#define FB_WS_N1  (FB_WS_G + NB * NR * G_STRIDE)
#define HS 264

// =====================================================================
// NEW PATH
// =====================================================================

// ---- prep: per-image Gram (f16, padded 48x68) + per-caption word norms ----
__global__ __launch_bounds__(256) void prep2_kernel(
    const float* __restrict__ im, const float* __restrict__ s,
    float* __restrict__ ws)
{
    const int b = blockIdx.x;
    const int t = threadIdx.x;
    __shared__ float s_imf[NR * 260];

    const float4* im4 = (const float4*)(im + (size_t)b * NR * ND);
    for (int i = t; i < NR * 64; i += 256) {
        int r = i >> 6, c4 = i & 63;
        *(float4*)&s_imf[r * 260 + 4 * c4] = im4[i];
    }
    _Float16* Gh = (_Float16*)(ws + WS_GH) + (size_t)b * GH_ELEMS;
    for (int i = t; i < GH_ELEMS / 2; i += 256) ((unsigned int*)Gh)[i] = 0u;
    __syncthreads();

    for (int i = t; i < NR * NR; i += 256) {
        int r = i / NR, rp = i - r * NR;
        const float4* a  = (const float4*)&s_imf[r * 260];
        const float4* bb = (const float4*)&s_imf[rp * 260];
        float acc = 0.f;
        for (int k = 0; k < 64; ++k) {
            float4 x = a[k], y = bb[k];
            acc += x.x * y.x + x.y * y.y + x.z * y.z + x.w * y.w;
        }
        Gh[r * 68 + rp] = (_Float16)acc;
    }

    const int w = t >> 3, g = t & 7;
    const float4* s4 = (const float4*)(s + (size_t)b * NW * ND);
    float acc = 0.f;
    for (int j = 0; j < 8; ++j) {
        float4 v = s4[w * 64 + g * 8 + j];
        acc += v.x * v.x + v.y * v.y + v.z * v.z + v.w * v.w;
    }
    acc += __shfl_down(acc, 4, 8);
    acc += __shfl_down(acc, 2, 8);
    acc += __shfl_down(acc, 1, 8);
    if (g == 0) ws[WS_N1 + b * NW + w] = sqrtf(acc);
}

// ---- GEMM: A0[m][n] = im[m] . cap[n]  (f16 out, [m][n] layout) ----
#define KHS 136
__global__ __launch_bounds__(512) void gemm_kernel(
    const float* __restrict__ im, const float* __restrict__ s,
    const int* __restrict__ s_l, float* __restrict__ ws)
{
    const int n0 = blockIdx.x * 128;   // caption-word rows
    const int m0 = blockIdx.y * 128;   // image-region rows
    const int t = threadIdx.x;
    __shared__ _Float16 sA[128 * KHS];
    __shared__ _Float16 sB[128 * KHS];

    const int i = t >> 2, q = t & 3;
    const int brow = n0 + i;
    const int slr = s_l[brow >> 5];
    const bool bz = ((brow & 31) >= slr);

    const int wave = t >> 6, lane = t & 63;
    const int mts = (wave & 3) * 2;
    const int nts = (wave >> 2) * 4;
    const int lm = lane & 15, kg = lane >> 4;

    f32x4 acc[2][4];
#pragma unroll
    for (int a_ = 0; a_ < 2; ++a_)
#pragma unroll
        for (int bn = 0; bn < 4; ++bn) acc[a_][bn] = (f32x4){0.f, 0.f, 0.f, 0.f};

    const float4* Ag = (const float4*)(im + (size_t)(m0 + i) * ND);
    const float4* Bg = (const float4*)(s + (size_t)brow * ND);

    for (int kk = 0; kk < 2; ++kk) {
#pragma unroll
        for (int j = 0; j < 8; ++j) {
            float4 av = Ag[kk * 32 + q + 4 * j];
            f16x4 ah;
            ah[0] = (_Float16)av.x; ah[1] = (_Float16)av.y;
            ah[2] = (_Float16)av.z; ah[3] = (_Float16)av.w;
            *(f16x4*)&sA[i * KHS + (q + 4 * j) * 4] = ah;
            f16x4 bh;
            if (bz) {
                bh[0] = bh[1] = bh[2] = bh[3] = (_Float16)0.f;
            } else {
                float4 bv = Bg[kk * 32 + q + 4 * j];
                bh[0] = (_Float16)bv.x; bh[1] = (_Float16)bv.y;
                bh[2] = (_Float16)bv.z; bh[3] = (_Float16)bv.w;
            }
            *(f16x4*)&sB[i * KHS + (q + 4 * j) * 4] = bh;
        }
        __syncthreads();
#pragma unroll
        for (int ks = 0; ks < 4; ++ks) {
            f16x8 af[2], bf[4];
#pragma unroll
            for (int mi = 0; mi < 2; ++mi)
                af[mi] = *(const f16x8*)&sA[((mts + mi) * 16 + lm) * KHS + ks * 32 + kg * 8];
#pragma unroll
            for (int ni = 0; ni < 4; ++ni)
                bf[ni] = *(const f16x8*)&sB[((nts + ni) * 16 + lm) * KHS + ks * 32 + kg * 8];
#pragma unroll
            for (int mi = 0; mi < 2; ++mi)
#pragma unroll
                for (int ni = 0; ni < 4; ++ni)
                    acc[mi][ni] = __builtin_amdgcn_mfma_f32_16x16x32_f16(af[mi], bf[ni], acc[mi][ni], 0, 0, 0);
        }
        __syncthreads();
    }

    // store [m][n]: lanes lm give consecutive n -> 32B-contiguous groups
    _Float16* A0 = (_Float16*)(ws + WS_A0);
#pragma unroll
    for (int mi = 0; mi < 2; ++mi)
#pragma unroll
        for (int ni = 0; ni < 4; ++ni) {
            const int n = n0 + (nts + ni) * 16 + lm;
            const int mBase = m0 + (mts + mi) * 16 + kg * 4;
#pragma unroll
            for (int v = 0; v < 4; ++v)
                A0[(size_t)(mBase + v) * LDA0 + n] = (_Float16)acc[mi][ni][v];
        }
}

// ---- glue2: block = (image b, 8 captions = 256 columns) ----
__global__ __launch_bounds__(256) void glue2_kernel(
    const int* __restrict__ s_l, const float* __restrict__ im_mask,
    float* __restrict__ ws)
{
    const int n0 = blockIdx.x * 256;   // global column base (c*32+w)
    const int b  = blockIdx.y;
    const int t  = threadIdx.x;

    __shared__ _Float16 s_raw[NR * 264];   // raw A0 tile [r][n]
    __shared__ _Float16 s_E[64 * 264];     // E tile, rows 36..63 zero (K-pad)
    __shared__ _Float16 s_G[48 * 68];
    __shared__ float s_coef[NR * 8];       // LAM / (||X||+eps) per (r, caption)
    __shared__ float s_m[NR];
    __shared__ float s_n2[256];
    __shared__ float s_n1c[256];
    __shared__ int   s_sl[8];

    // ---- stage raw tile: 36 rows x 512B contiguous ----
    const _Float16* A0 = (const _Float16*)(ws + WS_A0);
    for (int i = t; i < NR * 64; i += 256) {
        int r = i >> 6, ch = i & 63;
        *(f16x4*)&s_raw[r * 264 + ch * 4] =
            *(const f16x4*)(A0 + (size_t)(b * NR + r) * LDA0 + n0 + ch * 4);
    }
    // zero E K-pad rows 36..63
    for (int i = t; i < 28 * 64; i += 256) {
        int r = NR + (i >> 6), ch = i & 63;
        f16x4 z; z[0] = z[1] = z[2] = z[3] = (_Float16)0.f;
        *(f16x4*)&s_E[r * 264 + ch * 4] = z;
    }
    // stage G
    const _Float16* Gh = (const _Float16*)(ws + WS_GH) + (size_t)b * GH_ELEMS;
    for (int i = t; i < GH_ELEMS / 4; i += 256)
        *(f16x4*)&s_G[i * 4] = *(const f16x4*)(Gh + i * 4);
    if (t < NR) s_m[t] = im_mask[b * NR + t];
    s_n1c[t] = ws[WS_N1 + n0 + t];
    if (t < 8) s_sl[t] = s_l[(n0 >> 5) + t];
    __syncthreads();

    // ---- pass A: coef[r][p] = LAM / (sqrt(sum_w X^2) + eps) ----
    for (int i = t; i < NR * 8; i += 256) {
        int r = i >> 3, p = i & 7;
        const float one_m = 1.f - s_m[r];
        float ss = 0.f;
        const _Float16* row = &s_raw[r * 264 + p * 32];
#pragma unroll
        for (int j = 0; j < 8; ++j) {
            f16x4 h = *(const f16x4*)(row + 4 * j);
#pragma unroll
            for (int k2 = 0; k2 < 4; ++k2) {
                float raw = (float)h[k2];
                float X = (raw >= 0.f ? raw : 0.1f * raw) + one_m;
                ss += X * X;
            }
        }
        s_coef[r * 8 + p] = LAMf / (sqrtf(ss) + EPSf);
    }
    __syncthreads();

    // ---- pass B: per column n=t: E = exp(X*coef)*m; den, w12 in-regs ----
    float den = 0.f, W = 0.f;
    {
        const int p = t >> 5;
#pragma unroll
        for (int r = 0; r < NR; ++r) {
            float raw = (float)s_raw[r * 264 + t];
            float mm = s_m[r];
            float X = (raw >= 0.f ? raw : 0.1f * raw) + (1.f - mm);
            float E = __expf(X * s_coef[r * 8 + p]) * mm;
            den += E;
            W += E * raw;
            s_E[r * 264 + t] = (_Float16)E;
        }
    }
    __syncthreads();

    // ---- MFMA: D[n][r] = sum_k E[k][n]*G[r][k]; n2[n] = sum_r D*E[r][n] ----
    {
        const int wave = t >> 6, lane = t & 63;
        const int lm = lane & 15, kg = lane >> 4;
        f32x4 d[4][3];
#pragma unroll
        for (int tt = 0; tt < 4; ++tt)
#pragma unroll
            for (int rt = 0; rt < 3; ++rt) d[tt][rt] = (f32x4){0.f, 0.f, 0.f, 0.f};
#pragma unroll
        for (int ks = 0; ks < 2; ++ks) {
            f16x8 af[4], bf[3];
#pragma unroll
            for (int tt = 0; tt < 4; ++tt) {
                const int n = (wave * 4 + tt) * 16 + lm;
                f16x8 a;
#pragma unroll
                for (int j = 0; j < 8; ++j)
                    a[j] = s_E[(ks * 32 + kg * 8 + j) * 264 + n];
                af[tt] = a;
            }
#pragma unroll
            for (int rt = 0; rt < 3; ++rt)
                bf[rt] = *(const f16x8*)&s_G[(rt * 16 + lm) * 68 + ks * 32 + kg * 8];
#pragma unroll
            for (int tt = 0; tt < 4; ++tt)
#pragma unroll
                for (int rt = 0; rt < 3; ++rt)
                    d[tt][rt] = __builtin_amdgcn_mfma_f32_16x16x32_f16(af[tt], bf[rt], d[tt][rt], 0, 0, 0);
        }
#pragma unroll
        for (int tt = 0; tt < 4; ++tt) {
#pragma unroll
            for (int v = 0; v < 4; ++v) {
                const int n = (wave * 4 + tt) * 16 + kg * 4 + v;
                float p2 = 0.f;
#pragma unroll
                for (int rt = 0; rt < 3; ++rt)
                    p2 += d[tt][rt][v] * (float)s_E[(rt * 16 + lm) * 264 + n];
                p2 += __shfl_xor(p2, 1, 16);
                p2 += __shfl_xor(p2, 2, 16);
                p2 += __shfl_xor(p2, 4, 16);
                p2 += __shfl_xor(p2, 8, 16);
                if (lm == 0) s_n2[n] = p2;
            }
        }
    }
    __syncthreads();

    // ---- final: cos (denominators cancel), caption-sum, score ----
    {
        const int w = t & 31, p = t >> 5;
        const float n2 = fmaxf(s_n2[t], 0.f);
        const float cosv = W / fmaxf(s_n1c[t] * sqrtf(n2), EPSf * den);
        const int sl = s_sl[p];
        float val = (w < sl) ? cosv : 0.f;
        val += __shfl_xor(val, 1, 32);
        val += __shfl_xor(val, 2, 32);
        val += __shfl_xor(val, 4, 32);
        val += __shfl_xor(val, 8, 32);
        val += __shfl_xor(val, 16, 32);
        if (w == 0) ws[WS_SCORES + b * NB + (n0 >> 5) + p] = val / (float)sl;
    }
}

// =====================================================================
// FALLBACK PATH (used only if ws_size too small)
// =====================================================================
__global__ __launch_bounds__(256) void prep_fb_kernel(
    const float* __restrict__ im, const float* __restrict__ s,
    float* __restrict__ ws)
{
    const int b = blockIdx.x;
    const int t = threadIdx.x;
    __shared__ float s_imf[NR * 260];

    const float4* im4 = (const float4*)(im + (size_t)b * NR * ND);
    for (int i = t; i < NR * (ND / 4); i += 256) {
        int r = i >> 6, c4 = i & 63;
        *(float4*)&s_imf[r * 260 + 4 * c4] = im4[i];
    }
    __syncthreads();

    float* G = ws + FB_WS_G + (size_t)b * NR * G_STRIDE;
    for (int i = t; i < NR * NR; i += 256) {
        int r = i / NR, rp = i - r * NR;
        const float4* a  = (const float4*)&s_imf[r * 260];
        const float4* bb = (const float4*)&s_imf[rp * 260];
        float acc = 0.f;
        for (int k = 0; k < ND / 4; ++k) {
            float4 x = a[k], y = bb[k];
            acc += x.x * y.x + x.y * y.y + x.z * y.z + x.w * y.w;
        }
        G[r * G_STRIDE + rp] = acc;
    }

    const int w = t >> 3, g = t & 7;
    const float4* s4 = (const float4*)(s + (size_t)b * NW * ND);
    float acc = 0.f;
    for (int j = 0; j < 8; ++j) {
        float4 v = s4[w * 64 + g * 8 + j];
        acc += v.x * v.x + v.y * v.y + v.z * v.z + v.w * v.w;
    }
    acc += __shfl_down(acc, 4, 8);
    acc += __shfl_down(acc, 2, 8);
    acc += __shfl_down(acc, 1, 8);
    if (g == 0) ws[FB_WS_N1 + b * NW + w] = sqrtf(acc);
}

__global__ __launch_bounds__(384) void scores_fb_kernel(
    const float* __restrict__ im, const float* __restrict__ s,
    const int* __restrict__ s_l, const float* __restrict__ im_mask,
    float* __restrict__ ws)
{
    const int c = blockIdx.x;
    const int b = blockIdx.y;
    const int t = threadIdx.x;

    __shared__ _Float16 s_imh[48 * HS];
    __shared__ _Float16 s_caph[NW * HS];
    __shared__ float s_A0[NR * 33];
    __shared__ float s_X[NR * 33];
    __shared__ float s_y[NW * 40];
    __shared__ float s_Gf[NR * G_STRIDE];
    __shared__ float s_nrm[NR];
    __shared__ float s_m[NR];
    __shared__ float s_p1[NW * 12];
    __shared__ float s_p2[NW * 12];

    const int sl = s_l[c];

    const float4* im4 = (const float4*)(im + (size_t)b * NR * ND);
    for (int i = t; i < NR * 32; i += 384) {
        int r = i >> 5, ch = i & 31;
        float4 a  = im4[r * 64 + ch * 2];
        float4 bb = im4[r * 64 + ch * 2 + 1];
        f16x8 h;
        h[0] = (_Float16)a.x;  h[1] = (_Float16)a.y;
        h[2] = (_Float16)a.z;  h[3] = (_Float16)a.w;
        h[4] = (_Float16)bb.x; h[5] = (_Float16)bb.y;
        h[6] = (_Float16)bb.z; h[7] = (_Float16)bb.w;
        *(f16x8*)&s_imh[r * HS + ch * 8] = h;
    }
    {
        unsigned int* z = (unsigned int*)&s_imh[NR * HS];
        for (int i = t; i < 12 * (HS / 2); i += 384) z[i] = 0u;
    }
    const float4* s4 = (const float4*)(s + (size_t)c * NW * ND);
    for (int i = t; i < NW * 32; i += 384) {
        int w = i >> 5, ch = i & 31;
        f16x8 h;
        if (w < sl) {
            float4 a  = s4[w * 64 + ch * 2];
            float4 bb = s4[w * 64 + ch * 2 + 1];
            h[0] = (_Float16)a.x;  h[1] = (_Float16)a.y;
            h[2] = (_Float16)a.z;  h[3] = (_Float16)a.w;
            h[4] = (_Float16)bb.x; h[5] = (_Float16)bb.y;
            h[6] = (_Float16)bb.z; h[7] = (_Float16)bb.w;
        } else {
#pragma unroll
            for (int k = 0; k < 8; ++k) h[k] = (_Float16)0.f;
        }
        *(f16x8*)&s_caph[w * HS + ch * 8] = h;
    }
    {
        const float4* Gg = (const float4*)(ws + FB_WS_G + (size_t)b * NR * G_STRIDE);
        float4* Gs = (float4*)s_Gf;
        for (int i = t; i < NR * 9; i += 384) {
            int r = i / 9, q = i - r * 9;
            Gs[r * 10 + q] = Gg[r * 10 + q];
        }
    }
    if (t < NR) s_m[t] = im_mask[b * NR + t];
    __syncthreads();

    {
        const int wave = t >> 6, lane = t & 63;
        const int r0 = (wave >> 1) * 16, w0 = (wave & 1) * 16;
        const int m = lane & 15, kg = lane >> 4;
        f32x4 acc = {0.f, 0.f, 0.f, 0.f};
        const _Float16* ap = &s_imh[(r0 + m) * HS + kg * 8];
        const _Float16* bp = &s_caph[(w0 + m) * HS + kg * 8];
#pragma unroll
        for (int ks = 0; ks < 8; ++ks) {
            f16x8 av = *(const f16x8*)(ap + ks * 32);
            f16x8 bv = *(const f16x8*)(bp + ks * 32);
            acc = __builtin_amdgcn_mfma_f32_16x16x32_f16(av, bv, acc, 0, 0, 0);
        }
        const int wcol = w0 + m;
        const int rbase = r0 + kg * 4;
#pragma unroll
        for (int v = 0; v < 4; ++v) {
            int r = rbase + v;
            if (r < NR) {
                float rawv = acc[v];
                s_A0[r * 33 + wcol] = rawv;
                float lk = rawv >= 0.f ? rawv : 0.1f * rawv;
                s_X[r * 33 + wcol] = lk + (1.f - s_m[r]);
            }
        }
    }
    __syncthreads();

    if (t < NR) {
        float sum = 0.f;
        for (int w = 0; w < NW; ++w) { float x = s_X[t * 33 + w]; sum += x * x; }
        s_nrm[t] = sqrtf(sum) + EPSf;
    }
    __syncthreads();

    if (t < NW) {
        float xs[NR];
        float mx = -1e30f;
#pragma unroll
        for (int r = 0; r < NR; ++r) {
            float a = s_X[r * 33 + t] / s_nrm[r] * s_m[r] * LAMf;
            xs[r] = a; mx = fmaxf(mx, a);
        }
        float sum = 0.f;
#pragma unroll
        for (int r = 0; r < NR; ++r) {
            float e = __expf(xs[r] - mx) * s_m[r];
            xs[r] = e; sum += e;
        }
        float inv = 1.f / sum;
#pragma unroll
        for (int r = 0; r < NR; ++r) s_y[t * 40 + r] = xs[r] * inv;
    }
    __syncthreads();

    if (t < 288) {
        const int w = t / 9, q = t - (t / 9) * 9;
        float4 y4 = *(const float4*)&s_y[w * 40 + q * 4];
        float4 acc4 = {0.f, 0.f, 0.f, 0.f};
        float w12p = 0.f;
#pragma unroll
        for (int r = 0; r < NR; ++r) {
            float yr = s_y[w * 40 + r];
            float4 g4 = *(const float4*)&s_Gf[r * G_STRIDE + q * 4];
            acc4.x += yr * g4.x; acc4.y += yr * g4.y;
            acc4.z += yr * g4.z; acc4.w += yr * g4.w;
        }
        float n2p = acc4.x * y4.x + acc4.y * y4.y + acc4.z * y4.z + acc4.w * y4.w;
#pragma unroll
        for (int k = 0; k < 4; ++k) {
            int r = q * 4 + k;
            w12p += s_y[w * 40 + r] * s_A0[r * 33 + w];
        }
        s_p1[w * 12 + q] = w12p;
        s_p2[w * 12 + q] = n2p;
    }
    __syncthreads();

    if (t < NW) {
        float w12v = 0.f, n2v = 0.f;
        for (int q = 0; q < 9; ++q) { w12v += s_p1[t * 12 + q]; n2v += s_p2[t * 12 + q]; }
        float n1v = ws[FB_WS_N1 + c * NW + t];
        float cosv = w12v / fmaxf(n1v * sqrtf(n2v), EPSf);
        float val = (t < sl) ? cosv : 0.f;
#pragma unroll
        for (int k = 16; k; k >>= 1) val += __shfl_down(val, k, 32);
        if (t == 0) ws[WS_SCORES + b * NB + c] = val / (float)sl;
    }
}

// ---------------- contrastive loss over 128x128 scores ----------------
__global__ __launch_bounds__(128) void loss_kernel(
    const float* __restrict__ scores, const int* __restrict__ qid,
    float* __restrict__ out)
{
    __shared__ int   s_q[NB];
    __shared__ float s_c[NB];
    __shared__ float s_v[NB];
    const int i = threadIdx.x;
    s_q[i] = qid[i];
    __syncthreads();

    const int q = s_q[i];
    bool dup = false;
    for (int j = 0; j < i; ++j) dup = dup || (s_q[j] == q);

    const float* row = scores + i * NB;
    float mx = -1e30f;
    for (int j = 0; j < NB; ++j) {
        float l = (row[j] - ((j == i) ? MARGINf : 0.f)) * TEMPf;
        mx = fmaxf(mx, l);
    }
    float sum = 0.f;
    for (int j = 0; j < NB; ++j) {
        float l = (row[j] - ((j == i) ? MARGINf : 0.f)) * TEMPf;
        sum += expf(l - mx);
    }
    const float logZ = mx + logf(sum);
    const float picked = (row[i] - MARGINf) * TEMPf;
    const float valid = dup ? 0.f : 1.f;
    s_c[i] = (logZ - picked) * valid;
    s_v[i] = valid;
    __syncthreads();
    if (i == 0) {
        float a = 0.f, v = 0.f;
        for (int j = 0; j < NB; ++j) { a += s_c[j]; v += s_v[j]; }
        out[0] = a / fmaxf(v, 1.f);
    }
}

extern "C" void kernel_launch(void* const* d_in, const int* in_sizes, int n_in,
                              void* d_out, int out_size, void* d_ws, size_t ws_size,
                              hipStream_t stream) {
    const float* im      = (const float*)d_in[0];
    const float* s       = (const float*)d_in[1];
    const int*   s_l     = (const int*)d_in[2];
    const float* im_mask = (const float*)d_in[3];
    const int*   qid     = (const int*)d_in[4];

    float* ws  = (float*)d_ws;
    float* out = (float*)d_out;

    if (ws_size >= WS_NEED_BYTES) {
        prep2_kernel<<<NB, 256, 0, stream>>>(im, s, ws);
        gemm_kernel<<<dim3(32, 36), 512, 0, stream>>>(im, s, s_l, ws);
        glue2_kernel<<<dim3(16, NB), 256, 0, stream>>>(s_l, im_mask, ws);
    } else {
        prep_fb_kernel<<<NB, 256, 0, stream>>>(im, s, ws);
        dim3 grid(NB, NB);
        scores_fb_kernel<<<grid, 384, 0, stream>>>(im, s, s_l, im_mask, ws);
    }
    loss_kernel<<<1, 128, 0, stream>>>(ws + WS_SCORES, qid, out);
}

// Round 5
// 193.813 us; speedup vs baseline: 4.2949x; 1.0442x over previous
//
#include <hip/hip_runtime.h>
#include <hip/hip_bf16.h>
#include <math.h>

#define NB 128   // batch
#define NR 36    // regions
#define NW 32    // words
#define ND 256   // feature dim

#define MARGINf 0.05f
#define TEMPf   14.0f
#define LAMf    9.0f
#define EPSf    1e-8f

typedef _Float16 f16x8 __attribute__((ext_vector_type(8)));
typedef _Float16 f16x4 __attribute__((ext_vector_type(4)));
typedef float    f32x4 __attribute__((ext_vector_type(4)));

// ================= new-path workspace layout (float offsets) =================
// byte-identical footprint to round-3/4 layout (proven to fit in d_ws)
#define WS_SCORES 0
#define WS_N1     16384
#define WS_GH     20480                 // f16[128][48*68]
#define GH_ELEMS  (48 * 68)             // 3264 f16 per image
#define WS_A0     229376                // f16[4608][4096]  (row m = b*36+r, col n = c*32+w)
#define LDA0      4096
#define WS_NEED_BYTES ((size_t)(229376 + 9437184) * 4)   // 38,666,240 B

// ================= fallback (R2) workspace layout =================
#define G_STRIDE  40
#define FB_WS_G   (NB * NB)
#define FB_WS_N1  (FB_WS_G + NB * NR * G_STRIDE)
#define HS 264

// =====================================================================
// NEW PATH
// =====================================================================

// ---- prep: per-image Gram (f16, padded 48x68) + per-caption word norms ----
__global__ __launch_bounds__(256) void prep2_kernel(
    const float* __restrict__ im, const float* __restrict__ s,
    float* __restrict__ ws)
{
    const int b = blockIdx.x;
    const int t = threadIdx.x;
    __shared__ float s_imf[NR * 260];

    const float4* im4 = (const float4*)(im + (size_t)b * NR * ND);
    for (int i = t; i < NR * 64; i += 256) {
        int r = i >> 6, c4 = i & 63;
        *(float4*)&s_imf[r * 260 + 4 * c4] = im4[i];
    }
    _Float16* Gh = (_Float16*)(ws + WS_GH) + (size_t)b * GH_ELEMS;
    for (int i = t; i < GH_ELEMS / 2; i += 256) ((unsigned int*)Gh)[i] = 0u;
    __syncthreads();

    for (int i = t; i < NR * NR; i += 256) {
        int r = i / NR, rp = i - r * NR;
        const float4* a  = (const float4*)&s_imf[r * 260];
        const float4* bb = (const float4*)&s_imf[rp * 260];
        float acc = 0.f;
        for (int k = 0; k < 64; ++k) {
            float4 x = a[k], y = bb[k];
            acc += x.x * y.x + x.y * y.y + x.z * y.z + x.w * y.w;
        }
        Gh[r * 68 + rp] = (_Float16)acc;
    }

    const int w = t >> 3, g = t & 7;
    const float4* s4 = (const float4*)(s + (size_t)b * NW * ND);
    float acc = 0.f;
    for (int j = 0; j < 8; ++j) {
        float4 v = s4[w * 64 + g * 8 + j];
        acc += v.x * v.x + v.y * v.y + v.z * v.z + v.w * v.w;
    }
    acc += __shfl_down(acc, 4, 8);
    acc += __shfl_down(acc, 2, 8);
    acc += __shfl_down(acc, 1, 8);
    if (g == 0) ws[WS_N1 + b * NW + w] = sqrtf(acc);
}

// ---- GEMM: A0[m][n] = im[m] . cap[n]  (f16 out, [m][n] layout) ----
#define KHS 136
__global__ __launch_bounds__(512) void gemm_kernel(
    const float* __restrict__ im, const float* __restrict__ s,
    const int* __restrict__ s_l, float* __restrict__ ws)
{
    const int n0 = blockIdx.x * 128;   // caption-word rows
    const int m0 = blockIdx.y * 128;   // image-region rows
    const int t = threadIdx.x;
    __shared__ _Float16 sA[128 * KHS];
    __shared__ _Float16 sB[128 * KHS];

    const int i = t >> 2, q = t & 3;
    const int brow = n0 + i;
    const int slr = s_l[brow >> 5];
    const bool bz = ((brow & 31) >= slr);

    const int wave = t >> 6, lane = t & 63;
    const int mts = (wave & 3) * 2;
    const int nts = (wave >> 2) * 4;
    const int lm = lane & 15, kg = lane >> 4;

    f32x4 acc[2][4];
#pragma unroll
    for (int a_ = 0; a_ < 2; ++a_)
#pragma unroll
        for (int bn = 0; bn < 4; ++bn) acc[a_][bn] = (f32x4){0.f, 0.f, 0.f, 0.f};

    const float4* Ag = (const float4*)(im + (size_t)(m0 + i) * ND);
    const float4* Bg = (const float4*)(s + (size_t)brow * ND);

    for (int kk = 0; kk < 2; ++kk) {
#pragma unroll
        for (int j = 0; j < 8; ++j) {
            float4 av = Ag[kk * 32 + q + 4 * j];
            f16x4 ah;
            ah[0] = (_Float16)av.x; ah[1] = (_Float16)av.y;
            ah[2] = (_Float16)av.z; ah[3] = (_Float16)av.w;
            *(f16x4*)&sA[i * KHS + (q + 4 * j) * 4] = ah;
            f16x4 bh;
            if (bz) {
                bh[0] = bh[1] = bh[2] = bh[3] = (_Float16)0.f;
            } else {
                float4 bv = Bg[kk * 32 + q + 4 * j];
                bh[0] = (_Float16)bv.x; bh[1] = (_Float16)bv.y;
                bh[2] = (_Float16)bv.z; bh[3] = (_Float16)bv.w;
            }
            *(f16x4*)&sB[i * KHS + (q + 4 * j) * 4] = bh;
        }
        __syncthreads();
#pragma unroll
        for (int ks = 0; ks < 4; ++ks) {
            f16x8 af[2], bf[4];
#pragma unroll
            for (int mi = 0; mi < 2; ++mi)
                af[mi] = *(const f16x8*)&sA[((mts + mi) * 16 + lm) * KHS + ks * 32 + kg * 8];
#pragma unroll
            for (int ni = 0; ni < 4; ++ni)
                bf[ni] = *(const f16x8*)&sB[((nts + ni) * 16 + lm) * KHS + ks * 32 + kg * 8];
#pragma unroll
            for (int mi = 0; mi < 2; ++mi)
#pragma unroll
                for (int ni = 0; ni < 4; ++ni)
                    acc[mi][ni] = __builtin_amdgcn_mfma_f32_16x16x32_f16(af[mi], bf[ni], acc[mi][ni], 0, 0, 0);
        }
        __syncthreads();
    }

    // store [m][n]: lanes lm give consecutive n -> 32B-contiguous groups
    _Float16* A0 = (_Float16*)(ws + WS_A0);
#pragma unroll
    for (int mi = 0; mi < 2; ++mi)
#pragma unroll
        for (int ni = 0; ni < 4; ++ni) {
            const int n = n0 + (nts + ni) * 16 + lm;
            const int mBase = m0 + (mts + mi) * 16 + kg * 4;
#pragma unroll
            for (int v = 0; v < 4; ++v)
                A0[(size_t)(mBase + v) * LDA0 + n] = (_Float16)acc[mi][ni][v];
        }
}

// ---- glue3: block = (image b, 8 captions = 256 columns), low-LDS ----
// LDS ~39 KB -> 4 blocks/CU. A0 and G read straight from L2.
__global__ __launch_bounds__(256, 4) void glue3_kernel(
    const int* __restrict__ s_l, const float* __restrict__ im_mask,
    float* __restrict__ ws)
{
    const int n0 = blockIdx.x * 256;   // global column base (c*32+w)
    const int b  = blockIdx.y;
    const int t  = threadIdx.x;

    // E tile in A-operand-friendly layout: [n][k], k stride 72 f16 (144 B)
    __shared__ _Float16 s_E[256 * 72];     // 36,864 B
    __shared__ float s_coef[NR * 8];       // LAM/(||X||+eps) per (r, caption)
    __shared__ float s_n2[256];
    __shared__ float s_m[NR];
    __shared__ int   s_sl[8];

    const _Float16* A0 = (const _Float16*)(ws + WS_A0);
    const _Float16* Gh = (const _Float16*)(ws + WS_GH) + (size_t)b * GH_ELEMS;

    if (t < NR) s_m[t] = im_mask[b * NR + t];
    if (t < 8)  s_sl[t] = s_l[(n0 >> 5) + t];
    // zero K-pad of own row: k = 36..63
    {
        f16x4 z; z[0] = z[1] = z[2] = z[3] = (_Float16)0.f;
#pragma unroll
        for (int j = 0; j < 7; ++j)
            *(f16x4*)&s_E[t * 72 + 36 + 4 * j] = z;
    }
    __syncthreads();

    // ---- pass A: coef[r][p] = LAM / (sqrt(sum_w X^2) + eps), rows from L2 ----
    for (int i = t; i < NR * 8; i += 256) {
        const int r = i >> 3, p = i & 7;
        const _Float16* rowp = A0 + (size_t)(b * NR + r) * LDA0 + n0 + p * 32;
        const float one_m = 1.f - s_m[r];
        float ss = 0.f;
#pragma unroll
        for (int j = 0; j < 4; ++j) {
            f16x8 h = *(const f16x8*)(rowp + 8 * j);
#pragma unroll
            for (int k2 = 0; k2 < 8; ++k2) {
                float raw = (float)h[k2];
                float X = (raw >= 0.f ? raw : 0.1f * raw) + one_m;
                ss += X * X;
            }
        }
        s_coef[i] = LAMf / (sqrtf(ss) + EPSf);
    }
    __syncthreads();

    // ---- pass B: per column n=t: E = exp(X*coef)*m; den, W in registers ----
    float den = 0.f, W = 0.f;
    float n1v;
    {
        const int p = t >> 5;
        n1v = ws[WS_N1 + n0 + t];                  // early load, used in final
        const _Float16* colp = A0 + (size_t)b * NR * LDA0 + n0 + t;
        _Float16 rawh[NR];
#pragma unroll
        for (int r = 0; r < NR; ++r) rawh[r] = colp[(size_t)r * LDA0];
#pragma unroll
        for (int r4 = 0; r4 < 9; ++r4) {
            f16x4 pk;
#pragma unroll
            for (int j = 0; j < 4; ++j) {
                const int r = r4 * 4 + j;
                float raw = (float)rawh[r];
                float mm = s_m[r];
                float X = (raw >= 0.f ? raw : 0.1f * raw) + (1.f - mm);
                float E = __expf(X * s_coef[r * 8 + p]) * mm;
                den += E;
                W += E * raw;
                pk[j] = (_Float16)E;
            }
            *(f16x4*)&s_E[t * 72 + r4 * 4] = pk;
        }
    }
    __syncthreads();

    // ---- MFMA: D[n][r'] = sum_k E[n][k]*G[r'][k]; n2[n] = sum_r' D*E[n][r'] ----
    {
        const int wave = t >> 6, lane = t & 63;
        const int lm = lane & 15, kg = lane >> 4;
        f32x4 d[4][3];
#pragma unroll
        for (int tt = 0; tt < 4; ++tt)
#pragma unroll
            for (int rt = 0; rt < 3; ++rt) d[tt][rt] = (f32x4){0.f, 0.f, 0.f, 0.f};
#pragma unroll
        for (int ks = 0; ks < 2; ++ks) {
            f16x8 af[4], bf[3];
#pragma unroll
            for (int tt = 0; tt < 4; ++tt) {
                const int n = (wave * 4 + tt) * 16 + lm;
                af[tt] = *(const f16x8*)&s_E[n * 72 + ks * 32 + kg * 8];
            }
#pragma unroll
            for (int rt = 0; rt < 3; ++rt) {
                const _Float16* gp = Gh + (rt * 16 + lm) * 68 + ks * 32 + kg * 8;
                f16x4 lo = *(const f16x4*)gp;
                f16x4 hi = *(const f16x4*)(gp + 4);
                f16x8 g8;
                g8[0] = lo[0]; g8[1] = lo[1]; g8[2] = lo[2]; g8[3] = lo[3];
                g8[4] = hi[0]; g8[5] = hi[1]; g8[6] = hi[2]; g8[7] = hi[3];
                bf[rt] = g8;
            }
#pragma unroll
            for (int tt = 0; tt < 4; ++tt)
#pragma unroll
                for (int rt = 0; rt < 3; ++rt)
                    d[tt][rt] = __builtin_amdgcn_mfma_f32_16x16x32_f16(af[tt], bf[rt], d[tt][rt], 0, 0, 0);
        }
#pragma unroll
        for (int tt = 0; tt < 4; ++tt) {
#pragma unroll
            for (int v = 0; v < 4; ++v) {
                const int n = wave * 64 + tt * 16 + kg * 4 + v;
                float p2 = 0.f;
#pragma unroll
                for (int rt = 0; rt < 3; ++rt)
                    p2 += d[tt][rt][v] * (float)s_E[n * 72 + rt * 16 + lm];
                p2 += __shfl_xor(p2, 1, 16);
                p2 += __shfl_xor(p2, 2, 16);
                p2 += __shfl_xor(p2, 4, 16);
                p2 += __shfl_xor(p2, 8, 16);
                if (lm == 0) s_n2[n] = p2;
            }
        }
    }
    __syncthreads();

    // ---- final: cos (softmax denominators cancel), caption-sum, score ----
    {
        const int w = t & 31, p = t >> 5;
        const float n2 = fmaxf(s_n2[t], 0.f);
        const float cosv = W / fmaxf(n1v * sqrtf(n2), EPSf * den);
        const int sl = s_sl[p];
        float val = (w < sl) ? cosv : 0.f;
        val += __shfl_xor(val, 1, 32);
        val += __shfl_xor(val, 2, 32);
        val += __shfl_xor(val, 4, 32);
        val += __shfl_xor(val, 8, 32);
        val += __shfl_xor(val, 16, 32);
        if (w == 0) ws[WS_SCORES + b * NB + (n0 >> 5) + p] = val / (float)sl;
    }
}

// =====================================================================
// FALLBACK PATH (used only if ws_size too small)
// =====================================================================
__global__ __launch_bounds__(256) void prep_fb_kernel(
    const float* __restrict__ im, const float* __restrict__ s,
    float* __restrict__ ws)
{
    const int b = blockIdx.x;
    const int t = threadIdx.x;
    __shared__ float s_imf[NR * 260];

    const float4* im4 = (const float4*)(im + (size_t)b * NR * ND);
    for (int i = t; i < NR * (ND / 4); i += 256) {
        int r = i >> 6, c4 = i & 63;
        *(float4*)&s_imf[r * 260 + 4 * c4] = im4[i];
    }
    __syncthreads();

    float* G = ws + FB_WS_G + (size_t)b * NR * G_STRIDE;
    for (int i = t; i < NR * NR; i += 256) {
        int r = i / NR, rp = i - r * NR;
        const float4* a  = (const float4*)&s_imf[r * 260];
        const float4* bb = (const float4*)&s_imf[rp * 260];
        float acc = 0.f;
        for (int k = 0; k < ND / 4; ++k) {
            float4 x = a[k], y = bb[k];
            acc += x.x * y.x + x.y * y.y + x.z * y.z + x.w * y.w;
        }
        G[r * G_STRIDE + rp] = acc;
    }

    const int w = t >> 3, g = t & 7;
    const float4* s4 = (const float4*)(s + (size_t)b * NW * ND);
    float acc = 0.f;
    for (int j = 0; j < 8; ++j) {
        float4 v = s4[w * 64 + g * 8 + j];
        acc += v.x * v.x + v.y * v.y + v.z * v.z + v.w * v.w;
    }
    acc += __shfl_down(acc, 4, 8);
    acc += __shfl_down(acc, 2, 8);
    acc += __shfl_down(acc, 1, 8);
    if (g == 0) ws[FB_WS_N1 + b * NW + w] = sqrtf(acc);
}

__global__ __launch_bounds__(384) void scores_fb_kernel(
    const float* __restrict__ im, const float* __restrict__ s,
    const int* __restrict__ s_l, const float* __restrict__ im_mask,
    float* __restrict__ ws)
{
    const int c = blockIdx.x;
    const int b = blockIdx.y;
    const int t = threadIdx.x;

    __shared__ _Float16 s_imh[48 * HS];
    __shared__ _Float16 s_caph[NW * HS];
    __shared__ float s_A0[NR * 33];
    __shared__ float s_X[NR * 33];
    __shared__ float s_y[NW * 40];
    __shared__ float s_Gf[NR * G_STRIDE];
    __shared__ float s_nrm[NR];
    __shared__ float s_m[NR];
    __shared__ float s_p1[NW * 12];
    __shared__ float s_p2[NW * 12];

    const int sl = s_l[c];

    const float4* im4 = (const float4*)(im + (size_t)b * NR * ND);
    for (int i = t; i < NR * 32; i += 384) {
        int r = i >> 5, ch = i & 31;
        float4 a  = im4[r * 64 + ch * 2];
        float4 bb = im4[r * 64 + ch * 2 + 1];
        f16x8 h;
        h[0] = (_Float16)a.x;  h[1] = (_Float16)a.y;
        h[2] = (_Float16)a.z;  h[3] = (_Float16)a.w;
        h[4] = (_Float16)bb.x; h[5] = (_Float16)bb.y;
        h[6] = (_Float16)bb.z; h[7] = (_Float16)bb.w;
        *(f16x8*)&s_imh[r * HS + ch * 8] = h;
    }
    {
        unsigned int* z = (unsigned int*)&s_imh[NR * HS];
        for (int i = t; i < 12 * (HS / 2); i += 384) z[i] = 0u;
    }
    const float4* s4 = (const float4*)(s + (size_t)c * NW * ND);
    for (int i = t; i < NW * 32; i += 384) {
        int w = i >> 5, ch = i & 31;
        f16x8 h;
        if (w < sl) {
            float4 a  = s4[w * 64 + ch * 2];
            float4 bb = s4[w * 64 + ch * 2 + 1];
            h[0] = (_Float16)a.x;  h[1] = (_Float16)a.y;
            h[2] = (_Float16)a.z;  h[3] = (_Float16)a.w;
            h[4] = (_Float16)bb.x; h[5] = (_Float16)bb.y;
            h[6] = (_Float16)bb.z; h[7] = (_Float16)bb.w;
        } else {
#pragma unroll
            for (int k = 0; k < 8; ++k) h[k] = (_Float16)0.f;
        }
        *(f16x8*)&s_caph[w * HS + ch * 8] = h;
    }
    {
        const float4* Gg = (const float4*)(ws + FB_WS_G + (size_t)b * NR * G_STRIDE);
        float4* Gs = (float4*)s_Gf;
        for (int i = t; i < NR * 9; i += 384) {
            int r = i / 9, q = i - r * 9;
            Gs[r * 10 + q] = Gg[r * 10 + q];
        }
    }
    if (t < NR) s_m[t] = im_mask[b * NR + t];
    __syncthreads();

    {
        const int wave = t >> 6, lane = t & 63;
        const int r0 = (wave >> 1) * 16, w0 = (wave & 1) * 16;
        const int m = lane & 15, kg = lane >> 4;
        f32x4 acc = {0.f, 0.f, 0.f, 0.f};
        const _Float16* ap = &s_imh[(r0 + m) * HS + kg * 8];
        const _Float16* bp = &s_caph[(w0 + m) * HS + kg * 8];
#pragma unroll
        for (int ks = 0; ks < 8; ++ks) {
            f16x8 av = *(const f16x8*)(ap + ks * 32);
            f16x8 bv = *(const f16x8*)(bp + ks * 32);
            acc = __builtin_amdgcn_mfma_f32_16x16x32_f16(av, bv, acc, 0, 0, 0);
        }
        const int wcol = w0 + m;
        const int rbase = r0 + kg * 4;
#pragma unroll
        for (int v = 0; v < 4; ++v) {
            int r = rbase + v;
            if (r < NR) {
                float rawv = acc[v];
                s_A0[r * 33 + wcol] = rawv;
                float lk = rawv >= 0.f ? rawv : 0.1f * rawv;
                s_X[r * 33 + wcol] = lk + (1.f - s_m[r]);
            }
        }
    }
    __syncthreads();

    if (t < NR) {
        float sum = 0.f;
        for (int w = 0; w < NW; ++w) { float x = s_X[t * 33 + w]; sum += x * x; }
        s_nrm[t] = sqrtf(sum) + EPSf;
    }
    __syncthreads();

    if (t < NW) {
        float xs[NR];
        float mx = -1e30f;
#pragma unroll
        for (int r = 0; r < NR; ++r) {
            float a = s_X[r * 33 + t] / s_nrm[r] * s_m[r] * LAMf;
            xs[r] = a; mx = fmaxf(mx, a);
        }
        float sum = 0.f;
#pragma unroll
        for (int r = 0; r < NR; ++r) {
            float e = __expf(xs[r] - mx) * s_m[r];
            xs[r] = e; sum += e;
        }
        float inv = 1.f / sum;
#pragma unroll
        for (int r = 0; r < NR; ++r) s_y[t * 40 + r] = xs[r] * inv;
    }
    __syncthreads();

    if (t < 288) {
        const int w = t / 9, q = t - (t / 9) * 9;
        float4 y4 = *(const float4*)&s_y[w * 40 + q * 4];
        float4 acc4 = {0.f, 0.f, 0.f, 0.f};
        float w12p = 0.f;
#pragma unroll
        for (int r = 0; r < NR; ++r) {
            float yr = s_y[w * 40 + r];
            float4 g4 = *(const float4*)&s_Gf[r * G_STRIDE + q * 4];
            acc4.x += yr * g4.x; acc4.y += yr * g4.y;
            acc4.z += yr * g4.z; acc4.w += yr * g4.w;
        }
        float n2p = acc4.x * y4.x + acc4.y * y4.y + acc4.z * y4.z + acc4.w * y4.w;
#pragma unroll
        for (int k = 0; k < 4; ++k) {
            int r = q * 4 + k;
            w12p += s_y[w * 40 + r] * s_A0[r * 33 + w];
        }
        s_p1[w * 12 + q] = w12p;
        s_p2[w * 12 + q] = n2p;
    }
    __syncthreads();

    if (t < NW) {
        float w12v = 0.f, n2v = 0.f;
        for (int q = 0; q < 9; ++q) { w12v += s_p1[t * 12 + q]; n2v += s_p2[t * 12 + q]; }
        float n1v = ws[FB_WS_N1 + c * NW + t];
        float cosv = w12v / fmaxf(n1v * sqrtf(n2v), EPSf);
        float val = (t < sl) ? cosv : 0.f;
#pragma unroll
        for (int k = 16; k; k >>= 1) val += __shfl_down(val, k, 32);
        if (t == 0) ws[WS_SCORES + b * NB + c] = val / (float)sl;
    }
}

// ---------------- contrastive loss over 128x128 scores ----------------
__global__ __launch_bounds__(128) void loss_kernel(
    const float* __restrict__ scores, const int* __restrict__ qid,
    float* __restrict__ out)
{
    __shared__ int   s_q[NB];
    __shared__ float s_c[NB];
    __shared__ float s_v[NB];
    const int i = threadIdx.x;
    s_q[i] = qid[i];
    __syncthreads();

    const int q = s_q[i];
    bool dup = false;
    for (int j = 0; j < i; ++j) dup = dup || (s_q[j] == q);

    const float* row = scores + i * NB;
    float mx = -1e30f;
    for (int j = 0; j < NB; ++j) {
        float l = (row[j] - ((j == i) ? MARGINf : 0.f)) * TEMPf;
        mx = fmaxf(mx, l);
    }
    float sum = 0.f;
    for (int j = 0; j < NB; ++j) {
        float l = (row[j] - ((j == i) ? MARGINf : 0.f)) * TEMPf;
        sum += expf(l - mx);
    }
    const float logZ = mx + logf(sum);
    const float picked = (row[i] - MARGINf) * TEMPf;
    const float valid = dup ? 0.f : 1.f;
    s_c[i] = (logZ - picked) * valid;
    s_v[i] = valid;
    __syncthreads();
    if (i == 0) {
        float a = 0.f, v = 0.f;
        for (int j = 0; j < NB; ++j) { a += s_c[j]; v += s_v[j]; }
        out[0] = a / fmaxf(v, 1.f);
    }
}

extern "C" void kernel_launch(void* const* d_in, const int* in_sizes, int n_in,
                              void* d_out, int out_size, void* d_ws, size_t ws_size,
                              hipStream_t stream) {
    const float* im      = (const float*)d_in[0];
    const float* s       = (const float*)d_in[1];
    const int*   s_l     = (const int*)d_in[2];
    const float* im_mask = (const float*)d_in[3];
    const int*   qid     = (const int*)d_in[4];

    float* ws  = (float*)d_ws;
    float* out = (float*)d_out;

    if (ws_size >= WS_NEED_BYTES) {
        prep2_kernel<<<NB, 256, 0, stream>>>(im, s, ws);
        gemm_kernel<<<dim3(32, 36), 512, 0, stream>>>(im, s, s_l, ws);
        glue3_kernel<<<dim3(16, NB), 256, 0, stream>>>(s_l, im_mask, ws);
    } else {
        prep_fb_kernel<<<NB, 256, 0, stream>>>(im, s, ws);
        dim3 grid(NB, NB);
        scores_fb_kernel<<<grid, 384, 0, stream>>>(im, s, s_l, im_mask, ws);
    }
    loss_kernel<<<1, 128, 0, stream>>>(ws + WS_SCORES, qid, out);
}